// Round 5
// baseline (231.012 us; speedup 1.0000x reference)
//
#include <hip/hip_runtime.h>
#include <hip/hip_bf16.h>
#include <cstddef>

// Problem constants (match reference)
constexpr int NN = 20000;   // nodes
constexpr int NE = 320000;  // edges
constexpr int NHEAD = 4;
constexpr int HD = 512;     // H*D
constexpr int MPAD = 20096; // 314*64 padded rows for GEMM tiles
constexpr int SLOTS = 64;   // padded-CSR slots per node (Poisson(16): P(>64)~1e-20)
constexpr float NEG_SLOPE = 0.2f;

using short8 = __attribute__((ext_vector_type(8))) short;
using f32x4 = __attribute__((ext_vector_type(4))) float;

// async global->LDS, 16B per lane, LDS dest = wave-uniform base + lane*16
__device__ inline void gload16(const void* g, void* l) {
  __builtin_amdgcn_global_load_lds(
      (const __attribute__((address_space(1))) void*)g,
      (__attribute__((address_space(3))) void*)l, 16, 0, 0);
}

__device__ inline float fastrcp(float x) { return __builtin_amdgcn_rcpf(x); }

// fast ELU negative branch: 3-inst vs ~30-inst expm1f
__device__ inline float fast_elu(float x) {
  return (x > 0.f) ? x : (__expf(x) - 1.0f);
}

// ---------------- fused prep --------------------------------------------------
// Segments: [cnt zero][feats->bf16][W1^T bf16][vcombh bf16 swizzled]
//           [wl1t/wr1t][elq/er2 zero][out init (1 thread)]
// R4 lesson: layer-2 logits must be COMBINED + COMPACT before attn_q's edge
// gather (R4's per-edge 4-head combine = 29 MB HBM fetch, 69 us).  h1 atomics
// accumulate into elq[NN][8] (el 0-3, q 4-7 — one 32B line per edge gather)
// and er2[NN][4]; both zeroed here.
constexpr int S0 = NN;                      // cnt zero
constexpr int S1 = S0 + NN * 128 / 4;       // featsb (4 elems per item)
constexpr int S2 = S1 + 512 * 128;          // W1t
constexpr int S3 = S2 + 4 * 16 * 128;       // vcombh (8192)
constexpr int S4 = S3 + 1024;               // wl1t + wr1t (128*4 each, interleaved)
constexpr int S5 = S4 + 60000;              // elq+er2 zero (NN*12 floats, x4)
constexpr int S6 = S5 + 1;                  // out init
__global__ __launch_bounds__(256) void prep_kernel(
    const float* __restrict__ feats, const float* __restrict__ W1,
    const float* __restrict__ W2, const float* __restrict__ al1,
    const float* __restrict__ ar1, const float* __restrict__ al2,
    const float* __restrict__ ar2, const float* __restrict__ Wr,
    const float* __restrict__ b2, const float* __restrict__ br,
    __hip_bfloat16* __restrict__ featsb, __hip_bfloat16* __restrict__ W1t,
    __hip_bfloat16* __restrict__ vcombh, float* __restrict__ wl1t,
    float* __restrict__ wr1t, float* __restrict__ zero3,
    int* __restrict__ cnt, float* __restrict__ out) {
  int t = blockIdx.x * 256 + threadIdx.x;
  if (t < S0) {
    cnt[t] = 0;
  } else if (t < S1) {
    int u = (t - S0) * 4;                 // < NN*128 always (exact segment)
    float4 f = *reinterpret_cast<const float4*>(&feats[u]);
    __hip_bfloat162 o0 = __float22bfloat162_rn(make_float2(f.x, f.y));
    __hip_bfloat162 o1 = __float22bfloat162_rn(make_float2(f.z, f.w));
    uint2 pk;
    pk.x = *reinterpret_cast<unsigned int*>(&o0);
    pk.y = *reinterpret_cast<unsigned int*>(&o1);
    *reinterpret_cast<uint2*>(&featsb[u]) = pk;
  } else if (t < S2) {
    int u = t - S1;                       // W1t[col][k]
    W1t[u] = __float2bfloat16(W1[(size_t)(u & 127) * 512 + (u >> 7)]);
  } else if (t < S3) {
    int u = t - S2;                       // vcombh[head][m][kk]
    int head = u >> 11, rem = u & 2047;
    int m = rem >> 7, kk = rem & 127;
    float s = 0.f;
    if (m < 12) {
      int h = m & 3;
      const float* vec = (m < 4) ? (al2 + h * 128)
                       : (m < 8) ? (ar2 + h * 128) : Wr;
      const float* wrow = W2 + (size_t)(head * 128 + kk) * 512 + h * 128;
      for (int d = 0; d < 128; ++d) s += wrow[d] * vec[d];
    }
    int slot = kk >> 3, e = kk & 7;
    int sl = slot ^ (m & 7);
    vcombh[head * 2048 + m * 128 + sl * 8 + e] = __float2bfloat16(s);
  } else if (t < S4) {
    int u = t - S3;                       // wl1t/wr1t[d][h]
    int d = u >> 3, rem = u & 7, h = rem >> 1, sel = rem & 1;
    const float* vec = (sel ? ar1 : al1) + h * 128;
    const float* wrow = W1 + (size_t)d * 512 + h * 128;
    float s = 0.f;
    for (int dd = 0; dd < 128; ++dd) s += wrow[dd] * vec[dd];
    (sel ? wr1t : wl1t)[d * 4 + h] = s;
  } else if (t < S5) {
    int u = (t - S4) * 4;                 // elq + er2 contiguous zero
    *reinterpret_cast<float4*>(&zero3[u]) = make_float4(0.f, 0.f, 0.f, 0.f);
  } else if (t < S6) {
    float dot = 0.f;
    for (int i = 0; i < 512; ++i) dot += b2[i] * Wr[i & 127];
    out[0] = 0.25f * (float)NN * dot + (float)NN * br[0];
  }
}

// ---------------- CSR fill + layer-1 logits ---------------------------------
// el1[n,h] = feats[n] . wl1t[:,h]  (W1 folded through al1 -> no z needed).
// Grid-stride CSR fill prologue (cnt zeroed by prep), then one wave per node.
__global__ __launch_bounds__(256) void fill_logits_kernel(
    const int* __restrict__ src, const int* __restrict__ dst,
    int* __restrict__ cnt, int* __restrict__ src_perm,
    const __hip_bfloat16* __restrict__ featsb,
    const float* __restrict__ wl1t, const float* __restrict__ wr1t,
    float* __restrict__ el1, float* __restrict__ er1) {
  int t = threadIdx.x;
  {
    int nth = gridDim.x * 256;
    int gid = blockIdx.x * 256 + t;
    for (int e = gid; e < NE; e += nth) {
      int d = dst[e];
      int p = atomicAdd(&cnt[d], 1);
      if (p < SLOTS) src_perm[d * SLOTS + p] = src[e];
    }
  }
  int wv = t >> 6, lane = t & 63;
  int n = blockIdx.x * 4 + wv;
  unsigned int uu = *reinterpret_cast<const unsigned int*>(
      &featsb[(size_t)n * 128 + 2 * lane]);
  __hip_bfloat162 ub = *reinterpret_cast<__hip_bfloat162*>(&uu);
  float2 f = __bfloat1622float2(ub);
  float4 wlA = *reinterpret_cast<const float4*>(&wl1t[lane * 8]);
  float4 wlB = *reinterpret_cast<const float4*>(&wl1t[lane * 8 + 4]);
  float4 wrA = *reinterpret_cast<const float4*>(&wr1t[lane * 8]);
  float4 wrB = *reinterpret_cast<const float4*>(&wr1t[lane * 8 + 4]);
  float p0 = f.x * wlA.x + f.y * wlB.x;
  float p1 = f.x * wlA.y + f.y * wlB.y;
  float p2 = f.x * wlA.z + f.y * wlB.z;
  float p3 = f.x * wlA.w + f.y * wlB.w;
  float p4 = f.x * wrA.x + f.y * wrB.x;
  float p5 = f.x * wrA.y + f.y * wrB.y;
  float p6 = f.x * wrA.z + f.y * wrB.z;
  float p7 = f.x * wrA.w + f.y * wrB.w;
#pragma unroll
  for (int off = 1; off < 64; off <<= 1) {
    p0 += __shfl_xor(p0, off); p1 += __shfl_xor(p1, off);
    p2 += __shfl_xor(p2, off); p3 += __shfl_xor(p3, off);
    p4 += __shfl_xor(p4, off); p5 += __shfl_xor(p5, off);
    p6 += __shfl_xor(p6, off); p7 += __shfl_xor(p7, off);
  }
  if (lane == 0) {
    *reinterpret_cast<float4*>(&el1[n * 4]) = make_float4(p0, p1, p2, p3);
    *reinterpret_cast<float4*>(&er1[n * 4]) = make_float4(p4, p5, p6, p7);
  }
}

// ---------------- layer-1 attention + FEATS aggregation ---------------------
// Aggregate feats (256 B/edge, 5.1 MB footprint) — W1 applied AFTER the
// alpha-weighted sum (linearity).  One wave per node.
__global__ __launch_bounds__(256) void gather_kernel(
    const __hip_bfloat16* __restrict__ featsb,
    const int* __restrict__ cnt, const int* __restrict__ src_perm,
    const float* __restrict__ el, const float* __restrict__ er,
    __hip_bfloat16* __restrict__ aggb) {         // [MPAD][4*128] bf16
  __shared__ float4 alph[4][SLOTS];
  __shared__ int srcb[4][SLOTS];
  int wv = __builtin_amdgcn_readfirstlane((int)(threadIdx.x >> 6));
  int n = blockIdx.x * 4 + wv;
  int lane = threadIdx.x & 63;
  int c = min(cnt[n], SLOTS);

  // ---- phase 1: attention coefficients (lane = slot) ----
  {
    float4 er4 = *reinterpret_cast<const float4*>(&er[n * 4]);
    float a0 = 0.f, a1 = 0.f, a2 = 0.f, a3 = 0.f;
    int sv = 0;
    if (lane < c) {
      sv = src_perm[n * SLOTS + lane];
      float4 e4 = *reinterpret_cast<const float4*>(&el[sv * 4]);
      float x0 = e4.x + er4.x, x1 = e4.y + er4.y;
      float x2 = e4.z + er4.z, x3 = e4.w + er4.w;
      x0 = (x0 > 0.f) ? x0 : NEG_SLOPE * x0;
      x1 = (x1 > 0.f) ? x1 : NEG_SLOPE * x1;
      x2 = (x2 > 0.f) ? x2 : NEG_SLOPE * x2;
      x3 = (x3 > 0.f) ? x3 : NEG_SLOPE * x3;
      a0 = __expf(x0); a1 = __expf(x1); a2 = __expf(x2); a3 = __expf(x3);
    }
    float s0 = a0, s1 = a1, s2 = a2, s3 = a3;
#pragma unroll
    for (int off = 1; off < 64; off <<= 1) {
      s0 += __shfl_xor(s0, off);
      s1 += __shfl_xor(s1, off);
      s2 += __shfl_xor(s2, off);
      s3 += __shfl_xor(s3, off);
    }
    float i0 = fastrcp(fmaxf(s0, 1e-9f));
    float i1 = fastrcp(fmaxf(s1, 1e-9f));
    float i2 = fastrcp(fmaxf(s2, 1e-9f));
    float i3 = fastrcp(fmaxf(s3, 1e-9f));
    alph[wv][lane] = make_float4(a0 * i0, a1 * i1, a2 * i2, a3 * i3);
    srcb[wv][lane] = sv;   // same-wave producer/consumer, no barrier
  }

  // ---- phase 2: feats gather (lane = 2 dims), 4-deep unroll ----
  float acc[4][2] = {};

#define EB(IDX)                                                                \
  {                                                                            \
    float4 a4 = alph[wv][(IDX)];                                               \
    int s = srcb[wv][(IDX)];                                                   \
    unsigned int uu = *reinterpret_cast<const unsigned int*>(                  \
        &featsb[(size_t)s * 128 + 2 * lane]);                                  \
    __hip_bfloat162 ub = *reinterpret_cast<__hip_bfloat162*>(&uu);             \
    float2 f = __bfloat1622float2(ub);                                         \
    acc[0][0] += a4.x * f.x; acc[0][1] += a4.x * f.y;                          \
    acc[1][0] += a4.y * f.x; acc[1][1] += a4.y * f.y;                          \
    acc[2][0] += a4.z * f.x; acc[2][1] += a4.z * f.y;                          \
    acc[3][0] += a4.w * f.x; acc[3][1] += a4.w * f.y;                          \
  }

  int i = 0;
  for (; i + 3 < c; i += 4) {
    EB(i) EB(i + 1) EB(i + 2) EB(i + 3)
  }
  for (; i < c; ++i) EB(i)
#undef EB

  size_t obase = (size_t)n * HD + 2 * lane;
#pragma unroll
  for (int h = 0; h < 4; ++h) {
    __hip_bfloat162 o = __float22bfloat162_rn(make_float2(acc[h][0], acc[h][1]));
    *reinterpret_cast<unsigned int*>(&aggb[obase + h * 128]) =
        *reinterpret_cast<unsigned int*>(&o);
  }
}

// ---------------- h1 GEMM + MFMA 12-dot epilogue ----------------------------
// Zero shuffles (R2 lesson).  Atomic accumulation into COMPACT combined
// arrays (R4 lesson: per-edge head-combine in attn_q = 29 MB fetch; compact
// elq/er2 = 960 KB, L2-resident).  elq[NN][8] packs el(0-3)+q(4-7) so the
// layer-2 edge gather is ONE 32B line.
__global__ __launch_bounds__(256) void h1_gemm_kernel(
    const __hip_bfloat16* __restrict__ A,    // aggb [MPAD][512] bf16
    const __hip_bfloat16* __restrict__ Bt,   // W1t  [512][128] bf16
    const __hip_bfloat16* __restrict__ vcombh, // [4][16][128] bf16 pre-swizzled
    const float* __restrict__ b1,            // [512]
    float* __restrict__ elq,                 // [NN][8] el+q
    float* __restrict__ er2) {               // [NN][4]
  __shared__ short AsH[64 * 128];           // 16 KB: agg tile, then h1 tile
  __shared__ short Bs[128 * 128];           // 32 KB: W1t head-slice
  __shared__ short Vc[16 * 128];            // 4 KB: vcombh head-slice
  int t = threadIdx.x;
  int lane = t & 63, wave = t >> 6;
  int rowBase = blockIdx.x * 64;
  int head = blockIdx.y;
  int nloc = lane & 15;                     // free-dim index within fragment
  int quad = lane >> 4;

  // ---- single staging phase (source pre-swizzled, LDS linear) ----
#pragma unroll
  for (int p = 0; p < 4; ++p) {             // A: 64 rows x 16 slots
    int fbase = p * 256 + wave * 64;        // wave-uniform LDS base
    int f = fbase + lane;
    int row = f >> 4, slot = f & 15;
    int ss = slot ^ (row & 7);
    gload16(A + (size_t)(rowBase + row) * HD + head * 128 + ss * 8,
            AsH + fbase * 8);
  }
#pragma unroll
  for (int p = 0; p < 8; ++p) {             // B: 128 rows x 16 slots
    int fbase = p * 256 + wave * 64;
    int f = fbase + lane;
    int row = f >> 4, slot = f & 15;
    int ss = slot ^ (row & 7);
    gload16(Bt + (size_t)(head * 128 + row) * 128 + ss * 8,
            Bs + fbase * 8);
  }
  {
    int fbase = wave * 64;                  // Vc: already swizzled in global
    gload16(vcombh + head * 2048 + (size_t)(fbase + lane) * 8,
            Vc + fbase * 8);
  }
  __syncthreads();

  // ---- first GEMM: D[col][node], wave owns 16 nodes x all 128 cols ----
  f32x4 acc[8];
#pragma unroll
  for (int i = 0; i < 8; ++i) acc[i] = (f32x4){0.f, 0.f, 0.f, 0.f};
#pragma unroll
  for (int c = 0; c < 4; ++c) {
    int arow = wave * 16 + nloc;            // agg node row (B-operand)
    short8 bfr = *(const short8*)&AsH[arow * 128 +
                                      (((c << 2) + quad) ^ (arow & 7)) * 8];
#pragma unroll
    for (int i = 0; i < 8; ++i) {
      int brow = i * 16 + nloc;             // W1t col row (A-operand)
      short8 af = *(const short8*)&Bs[brow * 128 +
                                      (((c << 2) + quad) ^ (brow & 7)) * 8];
      acc[i] = __builtin_amdgcn_mfma_f32_16x16x32_bf16(af, bfr, acc[i], 0, 0, 0);
    }
  }

  // ---- elu(acc + b1) -> bf16 -> H1s (overlay on AsH, wave-local rows) ----
  int node = wave * 16 + nloc;
#pragma unroll
  for (int i = 0; i < 8; ++i) {
    float4 b4 = *reinterpret_cast<const float4*>(
        &b1[head * 128 + i * 16 + quad * 4]);
    float e0 = fast_elu(acc[i][0] + b4.x);
    float e1 = fast_elu(acc[i][1] + b4.y);
    float e2 = fast_elu(acc[i][2] + b4.z);
    float e3 = fast_elu(acc[i][3] + b4.w);
    __hip_bfloat162 p0 = __float22bfloat162_rn(make_float2(e0, e1));
    __hip_bfloat162 p1 = __float22bfloat162_rn(make_float2(e2, e3));
    uint2 pk;
    pk.x = *reinterpret_cast<unsigned int*>(&p0);
    pk.y = *reinterpret_cast<unsigned int*>(&p1);
    int slot = i * 2 + (quad >> 1);         // 16B slot of col i*16+quad*4
    int sub = quad & 1;                     // low/high 8B within slot
    int sl = slot ^ (node & 7);
    *reinterpret_cast<uint2*>(&AsH[node * 128 + sl * 8 + sub * 4]) = pk;
  }

  // ---- second GEMM: D2[vv][node] = Vc[16x128] . h1[128x16] ----
  f32x4 acc2 = (f32x4){0.f, 0.f, 0.f, 0.f};
#pragma unroll
  for (int c = 0; c < 4; ++c) {
    short8 a2 = *(const short8*)&Vc[nloc * 128 +
                                    (((c << 2) + quad) ^ (nloc & 7)) * 8];
    short8 b2 = *(const short8*)&AsH[node * 128 +
                                     (((c << 2) + quad) ^ (node & 7)) * 8];
    acc2 = __builtin_amdgcn_mfma_f32_16x16x32_bf16(a2, b2, acc2, 0, 0, 0);
  }

  // D2 layout: vv = quad*4 + r, node = lane&15; atomic k-slice combine into
  // the compact arrays (el -> elq[0:4], er -> er2, q -> elq[4:8])
  int gn = rowBase + node;
  if (gn < NN) {
    if (quad == 0) {
#pragma unroll
      for (int r = 0; r < 4; ++r)
        atomicAdd(&elq[(size_t)gn * 8 + r], acc2[r]);
    } else if (quad == 1) {
#pragma unroll
      for (int r = 0; r < 4; ++r)
        atomicAdd(&er2[(size_t)gn * 4 + r], acc2[r]);
    } else if (quad == 2) {
#pragma unroll
      for (int r = 0; r < 4; ++r)
        atomicAdd(&elq[(size_t)gn * 8 + 4 + r], acc2[r]);
    }
  }
}

// ---------------- layer-2 attention + readout dot ---------------------------
// Compact L2-resident operands: er2[n*4] once per node; per edge ONE 32B line
// elq[s][8] = el(4)+q(4).  Block partial atomicAdds 0.25*sum into out
// (initialized by prep; stream order guarantees init lands first).
__global__ __launch_bounds__(256) void attn_q_kernel(
    const int* __restrict__ src_perm,
    const int* __restrict__ cnt,
    const float* __restrict__ elq,          // [NN][8]
    const float* __restrict__ er2,          // [NN][4]
    float* __restrict__ out) {
  __shared__ float blk[4];
  int wv = __builtin_amdgcn_readfirstlane((int)(threadIdx.x >> 6));
  int n = blockIdx.x * 4 + wv;
  int lane = threadIdx.x & 63;
  int c = min(cnt[n], SLOTS);
  float4 er4 = *reinterpret_cast<const float4*>(&er2[n * 4]);
  float a0 = 0.f, a1 = 0.f, a2 = 0.f, a3 = 0.f;
  float4 q4 = make_float4(0.f, 0.f, 0.f, 0.f);
  if (lane < c) {
    int s = src_perm[n * SLOTS + lane];
    float4 e4 = *reinterpret_cast<const float4*>(&elq[(size_t)s * 8]);
    q4 = *reinterpret_cast<const float4*>(&elq[(size_t)s * 8 + 4]);
    float x0 = e4.x + er4.x, x1 = e4.y + er4.y;
    float x2 = e4.z + er4.z, x3 = e4.w + er4.w;
    x0 = (x0 > 0.f) ? x0 : NEG_SLOPE * x0;
    x1 = (x1 > 0.f) ? x1 : NEG_SLOPE * x1;
    x2 = (x2 > 0.f) ? x2 : NEG_SLOPE * x2;
    x3 = (x3 > 0.f) ? x3 : NEG_SLOPE * x3;
    a0 = __expf(x0); a1 = __expf(x1); a2 = __expf(x2); a3 = __expf(x3);
  }
  float s0 = a0, s1 = a1, s2 = a2, s3 = a3;
#pragma unroll
  for (int off = 1; off < 64; off <<= 1) {
    s0 += __shfl_xor(s0, off);
    s1 += __shfl_xor(s1, off);
    s2 += __shfl_xor(s2, off);
    s3 += __shfl_xor(s3, off);
  }
  float p = 0.f;
  if (lane < c) {
    p = (a0 * fastrcp(fmaxf(s0, 1e-9f))) * q4.x +
        (a1 * fastrcp(fmaxf(s1, 1e-9f))) * q4.y +
        (a2 * fastrcp(fmaxf(s2, 1e-9f))) * q4.z +
        (a3 * fastrcp(fmaxf(s3, 1e-9f))) * q4.w;
  }
#pragma unroll
  for (int off = 32; off > 0; off >>= 1) p += __shfl_down(p, off);
  if (lane == 0) blk[wv] = p;
  __syncthreads();
  if (threadIdx.x == 0) {
    atomicAdd(out, 0.25f * (blk[0] + blk[1] + blk[2] + blk[3]));
  }
}

// ---------------- launch ----------------
extern "C" void kernel_launch(void* const* d_in, const int* in_sizes, int n_in,
                              void* d_out, int out_size, void* d_ws, size_t ws_size,
                              hipStream_t stream) {
  const float* feats = (const float*)d_in[0];
  const int* src = (const int*)d_in[1];
  const int* dst = (const int*)d_in[2];
  const float* W1 = (const float*)d_in[3];
  const float* al1 = (const float*)d_in[4];
  const float* ar1 = (const float*)d_in[5];
  const float* b1 = (const float*)d_in[6];
  const float* W2 = (const float*)d_in[7];
  const float* al2 = (const float*)d_in[8];
  const float* ar2 = (const float*)d_in[9];
  const float* b2 = (const float*)d_in[10];
  const float* Wr = (const float*)d_in[11];
  const float* br = (const float*)d_in[12];
  float* out = (float*)d_out;

  // workspace layout (~33 MB); all section sizes multiples of 16 B
  __hip_bfloat16* featsb = (__hip_bfloat16*)d_ws;               // NN*128 bf16
  __hip_bfloat16* aggb = featsb + (size_t)NN * 128;             // MPAD*512 bf16
  __hip_bfloat16* W1t = aggb + (size_t)MPAD * HD;               // 512*128 bf16
  __hip_bfloat16* vcombh = W1t + 512 * 128;                     // 4*16*128 bf16
  float* wl1t = (float*)(vcombh + 4 * 16 * 128);                // 128*4 f32
  float* wr1t = wl1t + 512;                                     // 128*4 f32
  float* el1 = wr1t + 512;                                      // NN*4
  float* er1 = el1 + (size_t)NN * NHEAD;                        // NN*4
  float* elq = er1 + (size_t)NN * NHEAD;                        // NN*8
  float* er2 = elq + (size_t)NN * 8;                            // NN*4
  int* cnt = (int*)(er2 + (size_t)NN * NHEAD);                  // NN
  int* src_perm = cnt + NN;                                     // NN*SLOTS

  // prep: cnt zero + feats->bf16 + W1^T + vcombh + wl1t/wr1t + zeros + out init
  prep_kernel<<<(S6 + 255) / 256, 256, 0, stream>>>(
      feats, W1, W2, al1, ar1, al2, ar2, Wr, b2, br, featsb, W1t, vcombh,
      wl1t, wr1t, elq, cnt, out);

  // CSR fill + layer-1 logits (W1 folded — no z GEMM)
  fill_logits_kernel<<<NN / 4, 256, 0, stream>>>(
      src, dst, cnt, src_perm, featsb, wl1t, wr1t, el1, er1);

  // layer-1 attn + FEATS aggregation (256 B/edge)
  gather_kernel<<<NN / 4, 256, 0, stream>>>(featsb, cnt, src_perm, el1, er1,
                                            aggb);

  // agg @ W1 -> h1 (in-LDS) -> atomic combine into compact elq/er2
  dim3 h1grid(MPAD / 64, NHEAD);
  h1_gemm_kernel<<<h1grid, 256, 0, stream>>>(aggb, W1t, vcombh, b1, elq, er2);

  // layer-2 attention + readout dot; block partials atomic into out
  attn_q_kernel<<<NN / 4, 256, 0, stream>>>(src_perm, cnt, elq, er2, out);
}

// Round 6
// 170.886 us; speedup vs baseline: 1.3519x; 1.3519x over previous
//
#include <hip/hip_runtime.h>
#include <hip/hip_bf16.h>
#include <cstddef>

// Problem constants (match reference)
constexpr int NN = 20000;   // nodes
constexpr int NE = 320000;  // edges
constexpr int NHEAD = 4;
constexpr int HD = 512;     // H*D
constexpr int MPAD = 20096; // 314*64 padded rows for GEMM tiles
constexpr int SLOTS = 64;   // padded-CSR slots per node (Poisson(16): P(>64)~1e-20)
constexpr float NEG_SLOPE = 0.2f;

using short8 = __attribute__((ext_vector_type(8))) short;
using f32x4 = __attribute__((ext_vector_type(4))) float;

// async global->LDS, 16B per lane, LDS dest = wave-uniform base + lane*16
__device__ inline void gload16(const void* g, void* l) {
  __builtin_amdgcn_global_load_lds(
      (const __attribute__((address_space(1))) void*)g,
      (__attribute__((address_space(3))) void*)l, 16, 0, 0);
}

__device__ inline float fastrcp(float x) { return __builtin_amdgcn_rcpf(x); }

// fast ELU negative branch: 3-inst vs ~30-inst expm1f
__device__ inline float fast_elu(float x) {
  return (x > 0.f) ? x : (__expf(x) - 1.0f);
}

// ---------------- fused prep --------------------------------------------------
// Segments: [cnt zero][feats->bf16][W1^T bf16][vcombh bf16 swizzled]
//           [wl1t/wr1t][elq/er2 zero][partials zero]
// R5 lesson (falsified R4 theory): attn_q's 67us was NOT gather fetch — it was
// 5000 same-address atomicAdd(out) serializing cross-XCD (~30cy each ≈ 62us).
// Scalar accumulation goes back to 256 spread partial slots + tiny final
// reduce (R3-proven: attn_q was <15us in that shape).
constexpr int S0 = NN;                      // cnt zero
constexpr int S1 = S0 + NN * 128 / 4;       // featsb (4 elems per item)
constexpr int S2 = S1 + 512 * 128;          // W1t
constexpr int S3 = S2 + 4 * 16 * 128;       // vcombh (8192)
constexpr int S4 = S3 + 1024;               // wl1t + wr1t (128*4 each, interleaved)
constexpr int S5 = S4 + 60000;              // elq+er2 zero (NN*12 floats, x4)
constexpr int S6 = S5 + 256;                // partials zero
__global__ __launch_bounds__(256) void prep_kernel(
    const float* __restrict__ feats, const float* __restrict__ W1,
    const float* __restrict__ W2, const float* __restrict__ al1,
    const float* __restrict__ ar1, const float* __restrict__ al2,
    const float* __restrict__ ar2, const float* __restrict__ Wr,
    __hip_bfloat16* __restrict__ featsb, __hip_bfloat16* __restrict__ W1t,
    __hip_bfloat16* __restrict__ vcombh, float* __restrict__ wl1t,
    float* __restrict__ wr1t, float* __restrict__ zero3,
    float* __restrict__ partials, int* __restrict__ cnt) {
  int t = blockIdx.x * 256 + threadIdx.x;
  if (t < S0) {
    cnt[t] = 0;
  } else if (t < S1) {
    int u = (t - S0) * 4;                 // < NN*128 always (exact segment)
    float4 f = *reinterpret_cast<const float4*>(&feats[u]);
    __hip_bfloat162 o0 = __float22bfloat162_rn(make_float2(f.x, f.y));
    __hip_bfloat162 o1 = __float22bfloat162_rn(make_float2(f.z, f.w));
    uint2 pk;
    pk.x = *reinterpret_cast<unsigned int*>(&o0);
    pk.y = *reinterpret_cast<unsigned int*>(&o1);
    *reinterpret_cast<uint2*>(&featsb[u]) = pk;
  } else if (t < S2) {
    int u = t - S1;                       // W1t[col][k]
    W1t[u] = __float2bfloat16(W1[(size_t)(u & 127) * 512 + (u >> 7)]);
  } else if (t < S3) {
    int u = t - S2;                       // vcombh[head][m][kk]
    int head = u >> 11, rem = u & 2047;
    int m = rem >> 7, kk = rem & 127;
    float s = 0.f;
    if (m < 12) {
      int h = m & 3;
      const float* vec = (m < 4) ? (al2 + h * 128)
                       : (m < 8) ? (ar2 + h * 128) : Wr;
      const float* wrow = W2 + (size_t)(head * 128 + kk) * 512 + h * 128;
      for (int d = 0; d < 128; ++d) s += wrow[d] * vec[d];
    }
    int slot = kk >> 3, e = kk & 7;
    int sl = slot ^ (m & 7);
    vcombh[head * 2048 + m * 128 + sl * 8 + e] = __float2bfloat16(s);
  } else if (t < S4) {
    int u = t - S3;                       // wl1t/wr1t[d][h]
    int d = u >> 3, rem = u & 7, h = rem >> 1, sel = rem & 1;
    const float* vec = (sel ? ar1 : al1) + h * 128;
    const float* wrow = W1 + (size_t)d * 512 + h * 128;
    float s = 0.f;
    for (int dd = 0; dd < 128; ++dd) s += wrow[dd] * vec[dd];
    (sel ? wr1t : wl1t)[d * 4 + h] = s;
  } else if (t < S5) {
    int u = (t - S4) * 4;                 // elq + er2 contiguous zero
    *reinterpret_cast<float4*>(&zero3[u]) = make_float4(0.f, 0.f, 0.f, 0.f);
  } else if (t < S6) {
    partials[t - S5] = 0.f;
  }
}

// ---------------- CSR fill + layer-1 logits ---------------------------------
// el1[n,h] = feats[n] . wl1t[:,h]  (W1 folded through al1 -> no z needed).
// Grid-stride CSR fill prologue (cnt zeroed by prep), then one wave per node.
__global__ __launch_bounds__(256) void fill_logits_kernel(
    const int* __restrict__ src, const int* __restrict__ dst,
    int* __restrict__ cnt, int* __restrict__ src_perm,
    const __hip_bfloat16* __restrict__ featsb,
    const float* __restrict__ wl1t, const float* __restrict__ wr1t,
    float* __restrict__ el1, float* __restrict__ er1) {
  int t = threadIdx.x;
  {
    int nth = gridDim.x * 256;
    int gid = blockIdx.x * 256 + t;
    for (int e = gid; e < NE; e += nth) {
      int d = dst[e];
      int p = atomicAdd(&cnt[d], 1);
      if (p < SLOTS) src_perm[d * SLOTS + p] = src[e];
    }
  }
  int wv = t >> 6, lane = t & 63;
  int n = blockIdx.x * 4 + wv;
  unsigned int uu = *reinterpret_cast<const unsigned int*>(
      &featsb[(size_t)n * 128 + 2 * lane]);
  __hip_bfloat162 ub = *reinterpret_cast<__hip_bfloat162*>(&uu);
  float2 f = __bfloat1622float2(ub);
  float4 wlA = *reinterpret_cast<const float4*>(&wl1t[lane * 8]);
  float4 wlB = *reinterpret_cast<const float4*>(&wl1t[lane * 8 + 4]);
  float4 wrA = *reinterpret_cast<const float4*>(&wr1t[lane * 8]);
  float4 wrB = *reinterpret_cast<const float4*>(&wr1t[lane * 8 + 4]);
  float p0 = f.x * wlA.x + f.y * wlB.x;
  float p1 = f.x * wlA.y + f.y * wlB.y;
  float p2 = f.x * wlA.z + f.y * wlB.z;
  float p3 = f.x * wlA.w + f.y * wlB.w;
  float p4 = f.x * wrA.x + f.y * wrB.x;
  float p5 = f.x * wrA.y + f.y * wrB.y;
  float p6 = f.x * wrA.z + f.y * wrB.z;
  float p7 = f.x * wrA.w + f.y * wrB.w;
#pragma unroll
  for (int off = 1; off < 64; off <<= 1) {
    p0 += __shfl_xor(p0, off); p1 += __shfl_xor(p1, off);
    p2 += __shfl_xor(p2, off); p3 += __shfl_xor(p3, off);
    p4 += __shfl_xor(p4, off); p5 += __shfl_xor(p5, off);
    p6 += __shfl_xor(p6, off); p7 += __shfl_xor(p7, off);
  }
  if (lane == 0) {
    *reinterpret_cast<float4*>(&el1[n * 4]) = make_float4(p0, p1, p2, p3);
    *reinterpret_cast<float4*>(&er1[n * 4]) = make_float4(p4, p5, p6, p7);
  }
}

// ---------------- layer-1 attention + FEATS aggregation ---------------------
// Aggregate feats (256 B/edge, 5.1 MB footprint) — W1 applied AFTER the
// alpha-weighted sum (linearity).  One wave per node.
__global__ __launch_bounds__(256) void gather_kernel(
    const __hip_bfloat16* __restrict__ featsb,
    const int* __restrict__ cnt, const int* __restrict__ src_perm,
    const float* __restrict__ el, const float* __restrict__ er,
    __hip_bfloat16* __restrict__ aggb) {         // [MPAD][4*128] bf16
  __shared__ float4 alph[4][SLOTS];
  __shared__ int srcb[4][SLOTS];
  int wv = __builtin_amdgcn_readfirstlane((int)(threadIdx.x >> 6));
  int n = blockIdx.x * 4 + wv;
  int lane = threadIdx.x & 63;
  int c = min(cnt[n], SLOTS);

  // ---- phase 1: attention coefficients (lane = slot) ----
  {
    float4 er4 = *reinterpret_cast<const float4*>(&er[n * 4]);
    float a0 = 0.f, a1 = 0.f, a2 = 0.f, a3 = 0.f;
    int sv = 0;
    if (lane < c) {
      sv = src_perm[n * SLOTS + lane];
      float4 e4 = *reinterpret_cast<const float4*>(&el[sv * 4]);
      float x0 = e4.x + er4.x, x1 = e4.y + er4.y;
      float x2 = e4.z + er4.z, x3 = e4.w + er4.w;
      x0 = (x0 > 0.f) ? x0 : NEG_SLOPE * x0;
      x1 = (x1 > 0.f) ? x1 : NEG_SLOPE * x1;
      x2 = (x2 > 0.f) ? x2 : NEG_SLOPE * x2;
      x3 = (x3 > 0.f) ? x3 : NEG_SLOPE * x3;
      a0 = __expf(x0); a1 = __expf(x1); a2 = __expf(x2); a3 = __expf(x3);
    }
    float s0 = a0, s1 = a1, s2 = a2, s3 = a3;
#pragma unroll
    for (int off = 1; off < 64; off <<= 1) {
      s0 += __shfl_xor(s0, off);
      s1 += __shfl_xor(s1, off);
      s2 += __shfl_xor(s2, off);
      s3 += __shfl_xor(s3, off);
    }
    float i0 = fastrcp(fmaxf(s0, 1e-9f));
    float i1 = fastrcp(fmaxf(s1, 1e-9f));
    float i2 = fastrcp(fmaxf(s2, 1e-9f));
    float i3 = fastrcp(fmaxf(s3, 1e-9f));
    alph[wv][lane] = make_float4(a0 * i0, a1 * i1, a2 * i2, a3 * i3);
    srcb[wv][lane] = sv;   // same-wave producer/consumer, no barrier
  }

  // ---- phase 2: feats gather (lane = 2 dims), 4-deep unroll ----
  float acc[4][2] = {};

#define EB(IDX)                                                                \
  {                                                                            \
    float4 a4 = alph[wv][(IDX)];                                               \
    int s = srcb[wv][(IDX)];                                                   \
    unsigned int uu = *reinterpret_cast<const unsigned int*>(                  \
        &featsb[(size_t)s * 128 + 2 * lane]);                                  \
    __hip_bfloat162 ub = *reinterpret_cast<__hip_bfloat162*>(&uu);             \
    float2 f = __bfloat1622float2(ub);                                         \
    acc[0][0] += a4.x * f.x; acc[0][1] += a4.x * f.y;                          \
    acc[1][0] += a4.y * f.x; acc[1][1] += a4.y * f.y;                          \
    acc[2][0] += a4.z * f.x; acc[2][1] += a4.z * f.y;                          \
    acc[3][0] += a4.w * f.x; acc[3][1] += a4.w * f.y;                          \
  }

  int i = 0;
  for (; i + 3 < c; i += 4) {
    EB(i) EB(i + 1) EB(i + 2) EB(i + 3)
  }
  for (; i < c; ++i) EB(i)
#undef EB

  size_t obase = (size_t)n * HD + 2 * lane;
#pragma unroll
  for (int h = 0; h < 4; ++h) {
    __hip_bfloat162 o = __float22bfloat162_rn(make_float2(acc[h][0], acc[h][1]));
    *reinterpret_cast<unsigned int*>(&aggb[obase + h * 128]) =
        *reinterpret_cast<unsigned int*>(&o);
  }
}

// ---------------- h1 GEMM + MFMA 12-dot epilogue ----------------------------
// Zero shuffles (R2 lesson).  Atomic accumulation into COMPACT combined
// arrays (R4 lesson: pre-combine BEFORE the per-edge gather; elq/er2 = 960 KB,
// L2-resident).  elq[NN][8] packs el(0-3)+q(4-7) -> one 32B line per edge.
__global__ __launch_bounds__(256) void h1_gemm_kernel(
    const __hip_bfloat16* __restrict__ A,    // aggb [MPAD][512] bf16
    const __hip_bfloat16* __restrict__ Bt,   // W1t  [512][128] bf16
    const __hip_bfloat16* __restrict__ vcombh, // [4][16][128] bf16 pre-swizzled
    const float* __restrict__ b1,            // [512]
    float* __restrict__ elq,                 // [NN][8] el+q
    float* __restrict__ er2) {               // [NN][4]
  __shared__ short AsH[64 * 128];           // 16 KB: agg tile, then h1 tile
  __shared__ short Bs[128 * 128];           // 32 KB: W1t head-slice
  __shared__ short Vc[16 * 128];            // 4 KB: vcombh head-slice
  int t = threadIdx.x;
  int lane = t & 63, wave = t >> 6;
  int rowBase = blockIdx.x * 64;
  int head = blockIdx.y;
  int nloc = lane & 15;                     // free-dim index within fragment
  int quad = lane >> 4;

  // ---- single staging phase (source pre-swizzled, LDS linear) ----
#pragma unroll
  for (int p = 0; p < 4; ++p) {             // A: 64 rows x 16 slots
    int fbase = p * 256 + wave * 64;        // wave-uniform LDS base
    int f = fbase + lane;
    int row = f >> 4, slot = f & 15;
    int ss = slot ^ (row & 7);
    gload16(A + (size_t)(rowBase + row) * HD + head * 128 + ss * 8,
            AsH + fbase * 8);
  }
#pragma unroll
  for (int p = 0; p < 8; ++p) {             // B: 128 rows x 16 slots
    int fbase = p * 256 + wave * 64;
    int f = fbase + lane;
    int row = f >> 4, slot = f & 15;
    int ss = slot ^ (row & 7);
    gload16(Bt + (size_t)(head * 128 + row) * 128 + ss * 8,
            Bs + fbase * 8);
  }
  {
    int fbase = wave * 64;                  // Vc: already swizzled in global
    gload16(vcombh + head * 2048 + (size_t)(fbase + lane) * 8,
            Vc + fbase * 8);
  }
  __syncthreads();

  // ---- first GEMM: D[col][node], wave owns 16 nodes x all 128 cols ----
  f32x4 acc[8];
#pragma unroll
  for (int i = 0; i < 8; ++i) acc[i] = (f32x4){0.f, 0.f, 0.f, 0.f};
#pragma unroll
  for (int c = 0; c < 4; ++c) {
    int arow = wave * 16 + nloc;            // agg node row (B-operand)
    short8 bfr = *(const short8*)&AsH[arow * 128 +
                                      (((c << 2) + quad) ^ (arow & 7)) * 8];
#pragma unroll
    for (int i = 0; i < 8; ++i) {
      int brow = i * 16 + nloc;             // W1t col row (A-operand)
      short8 af = *(const short8*)&Bs[brow * 128 +
                                      (((c << 2) + quad) ^ (brow & 7)) * 8];
      acc[i] = __builtin_amdgcn_mfma_f32_16x16x32_bf16(af, bfr, acc[i], 0, 0, 0);
    }
  }

  // ---- elu(acc + b1) -> bf16 -> H1s (overlay on AsH, wave-local rows) ----
  int node = wave * 16 + nloc;
#pragma unroll
  for (int i = 0; i < 8; ++i) {
    float4 b4 = *reinterpret_cast<const float4*>(
        &b1[head * 128 + i * 16 + quad * 4]);
    float e0 = fast_elu(acc[i][0] + b4.x);
    float e1 = fast_elu(acc[i][1] + b4.y);
    float e2 = fast_elu(acc[i][2] + b4.z);
    float e3 = fast_elu(acc[i][3] + b4.w);
    __hip_bfloat162 p0 = __float22bfloat162_rn(make_float2(e0, e1));
    __hip_bfloat162 p1 = __float22bfloat162_rn(make_float2(e2, e3));
    uint2 pk;
    pk.x = *reinterpret_cast<unsigned int*>(&p0);
    pk.y = *reinterpret_cast<unsigned int*>(&p1);
    int slot = i * 2 + (quad >> 1);         // 16B slot of col i*16+quad*4
    int sub = quad & 1;                     // low/high 8B within slot
    int sl = slot ^ (node & 7);
    *reinterpret_cast<uint2*>(&AsH[node * 128 + sl * 8 + sub * 4]) = pk;
  }

  // ---- second GEMM: D2[vv][node] = Vc[16x128] . h1[128x16] ----
  f32x4 acc2 = (f32x4){0.f, 0.f, 0.f, 0.f};
#pragma unroll
  for (int c = 0; c < 4; ++c) {
    short8 a2 = *(const short8*)&Vc[nloc * 128 +
                                    (((c << 2) + quad) ^ (nloc & 7)) * 8];
    short8 b2 = *(const short8*)&AsH[node * 128 +
                                     (((c << 2) + quad) ^ (node & 7)) * 8];
    acc2 = __builtin_amdgcn_mfma_f32_16x16x32_bf16(a2, b2, acc2, 0, 0, 0);
  }

  // D2 layout: vv = quad*4 + r, node = lane&15; atomic k-slice combine into
  // the compact arrays (el -> elq[0:4], er -> er2, q -> elq[4:8]).
  // 960K atomics over 960KB: ~4-way contention per address, pipelined — fine.
  int gn = rowBase + node;
  if (gn < NN) {
    if (quad == 0) {
#pragma unroll
      for (int r = 0; r < 4; ++r)
        atomicAdd(&elq[(size_t)gn * 8 + r], acc2[r]);
    } else if (quad == 1) {
#pragma unroll
      for (int r = 0; r < 4; ++r)
        atomicAdd(&er2[(size_t)gn * 4 + r], acc2[r]);
    } else if (quad == 2) {
#pragma unroll
      for (int r = 0; r < 4; ++r)
        atomicAdd(&elq[(size_t)gn * 8 + 4 + r], acc2[r]);
    }
  }
}

// ---------------- layer-2 attention + readout dot ---------------------------
// Compact L2-resident operands: er2[n*4] once per node; per edge ONE 32B line
// elq[s][8].  Block partial -> partials[bid & 255] (256 SPREAD slots — R5
// lesson: a single-address atomic serializes ~30cy x blocks = 62us).
__global__ __launch_bounds__(256) void attn_q_kernel(
    const int* __restrict__ src_perm,
    const int* __restrict__ cnt,
    const float* __restrict__ elq,          // [NN][8]
    const float* __restrict__ er2,          // [NN][4]
    float* __restrict__ partials) {         // [256]
  __shared__ float blk[4];
  int wv = __builtin_amdgcn_readfirstlane((int)(threadIdx.x >> 6));
  int n = blockIdx.x * 4 + wv;
  int lane = threadIdx.x & 63;
  int c = min(cnt[n], SLOTS);
  float4 er4 = *reinterpret_cast<const float4*>(&er2[n * 4]);
  float a0 = 0.f, a1 = 0.f, a2 = 0.f, a3 = 0.f;
  float4 q4 = make_float4(0.f, 0.f, 0.f, 0.f);
  if (lane < c) {
    int s = src_perm[n * SLOTS + lane];
    float4 e4 = *reinterpret_cast<const float4*>(&elq[(size_t)s * 8]);
    q4 = *reinterpret_cast<const float4*>(&elq[(size_t)s * 8 + 4]);
    float x0 = e4.x + er4.x, x1 = e4.y + er4.y;
    float x2 = e4.z + er4.z, x3 = e4.w + er4.w;
    x0 = (x0 > 0.f) ? x0 : NEG_SLOPE * x0;
    x1 = (x1 > 0.f) ? x1 : NEG_SLOPE * x1;
    x2 = (x2 > 0.f) ? x2 : NEG_SLOPE * x2;
    x3 = (x3 > 0.f) ? x3 : NEG_SLOPE * x3;
    a0 = __expf(x0); a1 = __expf(x1); a2 = __expf(x2); a3 = __expf(x3);
  }
  float s0 = a0, s1 = a1, s2 = a2, s3 = a3;
#pragma unroll
  for (int off = 1; off < 64; off <<= 1) {
    s0 += __shfl_xor(s0, off);
    s1 += __shfl_xor(s1, off);
    s2 += __shfl_xor(s2, off);
    s3 += __shfl_xor(s3, off);
  }
  float p = 0.f;
  if (lane < c) {
    p = (a0 * fastrcp(fmaxf(s0, 1e-9f))) * q4.x +
        (a1 * fastrcp(fmaxf(s1, 1e-9f))) * q4.y +
        (a2 * fastrcp(fmaxf(s2, 1e-9f))) * q4.z +
        (a3 * fastrcp(fmaxf(s3, 1e-9f))) * q4.w;
  }
#pragma unroll
  for (int off = 32; off > 0; off >>= 1) p += __shfl_down(p, off);
  if (lane == 0) blk[wv] = p;
  __syncthreads();
  if (threadIdx.x == 0) {
    atomicAdd(&partials[blockIdx.x & 255], blk[0] + blk[1] + blk[2] + blk[3]);
  }
}

// ---------------- final: out = 0.25*(sum partials + NN*b2.Wr_rep) + NN*br ----
__global__ __launch_bounds__(512) void final_kernel(
    const float* __restrict__ partials, const float* __restrict__ b2,
    const float* __restrict__ Wr, const float* __restrict__ br,
    float* __restrict__ out) {
  __shared__ float tmp[512];
  int t = threadIdx.x;
  float sum = (t < 256) ? partials[t] : 0.f;
  sum += (float)NN * b2[t] * Wr[t & 127];
  tmp[t] = sum;
  __syncthreads();
  for (int off = 256; off > 0; off >>= 1) {
    if (t < off) tmp[t] += tmp[t + off];
    __syncthreads();
  }
  if (t == 0) out[0] = 0.25f * tmp[0] + (float)NN * br[0];
}

// ---------------- launch ----------------
extern "C" void kernel_launch(void* const* d_in, const int* in_sizes, int n_in,
                              void* d_out, int out_size, void* d_ws, size_t ws_size,
                              hipStream_t stream) {
  const float* feats = (const float*)d_in[0];
  const int* src = (const int*)d_in[1];
  const int* dst = (const int*)d_in[2];
  const float* W1 = (const float*)d_in[3];
  const float* al1 = (const float*)d_in[4];
  const float* ar1 = (const float*)d_in[5];
  const float* b1 = (const float*)d_in[6];
  const float* W2 = (const float*)d_in[7];
  const float* al2 = (const float*)d_in[8];
  const float* ar2 = (const float*)d_in[9];
  const float* b2 = (const float*)d_in[10];
  const float* Wr = (const float*)d_in[11];
  const float* br = (const float*)d_in[12];
  float* out = (float*)d_out;

  // workspace layout (~33 MB); all section sizes multiples of 16 B
  __hip_bfloat16* featsb = (__hip_bfloat16*)d_ws;               // NN*128 bf16
  __hip_bfloat16* aggb = featsb + (size_t)NN * 128;             // MPAD*512 bf16
  __hip_bfloat16* W1t = aggb + (size_t)MPAD * HD;               // 512*128 bf16
  __hip_bfloat16* vcombh = W1t + 512 * 128;                     // 4*16*128 bf16
  float* wl1t = (float*)(vcombh + 4 * 16 * 128);                // 128*4 f32
  float* wr1t = wl1t + 512;                                     // 128*4 f32
  float* el1 = wr1t + 512;                                      // NN*4
  float* er1 = el1 + (size_t)NN * NHEAD;                        // NN*4
  float* elq = er1 + (size_t)NN * NHEAD;                        // NN*8
  float* er2 = elq + (size_t)NN * 8;                            // NN*4
  float* partials = er2 + (size_t)NN * NHEAD;                   // 256
  int* cnt = (int*)(partials + 256);                            // NN
  int* src_perm = cnt + NN;                                     // NN*SLOTS

  // prep: cnt zero + feats->bf16 + W1^T + vcombh + wl1t/wr1t + zeros
  prep_kernel<<<(S6 + 255) / 256, 256, 0, stream>>>(
      feats, W1, W2, al1, ar1, al2, ar2, Wr, featsb, W1t, vcombh, wl1t, wr1t,
      elq, partials, cnt);

  // CSR fill + layer-1 logits (W1 folded — no z GEMM)
  fill_logits_kernel<<<NN / 4, 256, 0, stream>>>(
      src, dst, cnt, src_perm, featsb, wl1t, wr1t, el1, er1);

  // layer-1 attn + FEATS aggregation (256 B/edge)
  gather_kernel<<<NN / 4, 256, 0, stream>>>(featsb, cnt, src_perm, el1, er1,
                                            aggb);

  // agg @ W1 -> h1 (in-LDS) -> atomic combine into compact elq/er2
  dim3 h1grid(MPAD / 64, NHEAD);
  h1_gemm_kernel<<<h1grid, 256, 0, stream>>>(aggb, W1t, vcombh, b1, elq, er2);

  // layer-2 attention + readout dot; spread partials then tiny final reduce
  attn_q_kernel<<<NN / 4, 256, 0, stream>>>(src_perm, cnt, elq, er2, partials);
  final_kernel<<<1, 512, 0, stream>>>(partials, b2, Wr, br, out);
}